// Round 1
// baseline (78.965 us; speedup 1.0000x reference)
//
#include <hip/hip_runtime.h>

// EatRxnLayer: h=0 (hunter), p=1 (prey), N=128.
// Output = [muTE (B,128) | ncovTE (B,128,128)] fp32, concatenated flat.
// ncovTE is zero except rows 0,1 and columns 0,1. Strategy:
//   1) hipMemsetAsync the whole output to 0 (bulk of the bytes, DMA speed)
//   2) fixup kernel writes the nonzero structure (~0.8 MB total)

#define NTOT 128

__global__ __launch_bounds__(NTOT)
void eat_rxn_fix(const float* __restrict__ mu,
                 const float* __restrict__ ncov,
                 float* __restrict__ out_mu,
                 float* __restrict__ out_ncov) {
    const int b = blockIdx.x;
    const int j = threadIdx.x;

    const float* murow = mu   + (size_t)b * NTOT;
    const float* crow0 = ncov + (size_t)b * NTOT * NTOT;
    float* omu = out_mu  + (size_t)b * NTOT;
    float* onc = out_ncov + (size_t)b * NTOT * NTOT;

    // coalesced: mu[b, j]
    float muj = murow[j];
    // ncov[b, j, 0..1] — h and p columns are adjacent; one aligned 8B load
    float2 cj = *reinterpret_cast<const float2*>(crow0 + (size_t)j * NTOT);

    // broadcast the 6 per-batch scalars via LDS
    __shared__ float s[6]; // mh, mp, chh, chp, cph, cpp
    if (j == 0) { s[0] = muj; s[2] = cj.x; s[3] = cj.y; } // chh=ncov[0,0], chp=ncov[0,1]
    if (j == 1) { s[1] = muj; s[4] = cj.x; s[5] = cj.y; } // cph=ncov[1,0], cpp=ncov[1,1]
    __syncthreads();
    const float mh = s[0], mp = s[1], chh = s[2], chp = s[3], cph = s[4], cpp = s[5];

    // n3_j = mu_j*(-2*mp*mh + cph) + mp*ncov[j,h] + mh*ncov[j,p]
    const float A  = -2.0f * mp * mh + cph;
    const float n3 = muj * A + mp * cj.x + mh * cj.y;

    // third moments for the 4 corner cells
    const float n3_pph = -2.0f*mp*mp*mh + 2.0f*mp*cph + mh*cpp;
    const float n3_hhp = -2.0f*mh*mh*mp + 2.0f*mh*chp + mp*chh;
    const float n3_hpp = -2.0f*mh*mp*mp + mh*cpp + 2.0f*mp*chp;
    const float vals_pp = -2.0f*n3_pph + chp;
    const float vals_hh =  2.0f*n3_hhp + chp;
    const float vals_hp = -n3_hhp + n3_hpp - chp;

    // row 0 (hunter row) and row 1 (prey row) — fully coalesced
    const float r0 = (j == 0) ? vals_hh : (j == 1) ? vals_hp :  n3;
    const float r1 = (j == 0) ? vals_hp : (j == 1) ? vals_pp : -n3;
    onc[j]        = r0;
    onc[NTOT + j] = r1;

    // columns 0,1 for rows j >= 2: ncovTE[b,j,0]=n3, ncovTE[b,j,1]=-n3
    if (j >= 2) {
        *reinterpret_cast<float2*>(onc + (size_t)j * NTOT) = make_float2(n3, -n3);
    }

    // muTE: only two nonzeros
    if (j == 0) { omu[0] = chp; omu[1] = -chp; }
}

extern "C" void kernel_launch(void* const* d_in, const int* in_sizes, int n_in,
                              void* d_out, int out_size, void* d_ws, size_t ws_size,
                              hipStream_t stream) {
    const float* mu   = (const float*)d_in[0];
    const float* ncov = (const float*)d_in[1];

    const int batch = in_sizes[0] / NTOT;

    float* out_mu   = (float*)d_out;
    float* out_ncov = out_mu + (size_t)batch * NTOT;

    // zero the entire output (muTE + ncovTE); fixup kernel overwrites nonzeros
    hipMemsetAsync(d_out, 0, (size_t)out_size * sizeof(float), stream);

    eat_rxn_fix<<<batch, NTOT, 0, stream>>>(mu, ncov, out_mu, out_ncov);
}

// Round 2
// 72.237 us; speedup vs baseline: 1.0931x; 1.0931x over previous
//
#include <hip/hip_runtime.h>

// EatRxnLayer: h=0 (hunter), p=1 (prey), N=128, BATCH=4096.
// Output = [muTE (B,128) | ncovTE (B,128,128)] fp32, flat.
// ncovTE is zero except rows 0,1 and columns 0,1 (+4 corner cells).
// R1 lesson: hipMemsetAsync's fill kernel runs at 1.7 TB/s (156 us) — it IS
// the bottleneck. Fuse: one kernel writes the whole output with float4 stores,
// composing {zero | row0 | row1 | col-pair} values in a single pass.

#define NTOT 128

__global__ __launch_bounds__(256)
void eat_rxn_fused(const float* __restrict__ mu,
                   const float* __restrict__ ncov,
                   float* __restrict__ out_mu,
                   float* __restrict__ out_ncov) {
    const int b = blockIdx.x;
    const int t = threadIdx.x;

    const float* __restrict__ murow = mu   + (size_t)b * NTOT;
    const float* __restrict__ crow  = ncov + (size_t)b * NTOT * NTOT;
    float* __restrict__ omu = out_mu  + (size_t)b * NTOT;
    float* __restrict__ onc = out_ncov + (size_t)b * NTOT * NTOT;

    __shared__ float  smu[NTOT];
    __shared__ float2 sc2[NTOT];     // ncov[b, j, 0:2]
    __shared__ float  srow0[NTOT];   // final ncovTE row 0
    __shared__ float  srow1[NTOT];   // final ncovTE row 1
    __shared__ float  scol[NTOT];    // n3_j  (col 0 value for rows j>=2; col 1 = -n3_j)
    __shared__ float  schp[1];

    // stage 1: load mu row + first-two-columns of ncov (coalesced-ish; 8B/row)
    if (t < NTOT) {
        smu[t] = murow[t];
        sc2[t] = *reinterpret_cast<const float2*>(crow + (size_t)t * NTOT);
    }
    __syncthreads();

    const float mh  = smu[0], mp  = smu[1];
    const float chh = sc2[0].x, chp = sc2[0].y;
    const float cph = sc2[1].x, cpp = sc2[1].y;

    // stage 2: per-j third moment n3_j and the 4 corner values
    if (t < NTOT) {
        const float A  = -2.0f * mp * mh + cph;
        const float n3 = smu[t] * A + mp * sc2[t].x + mh * sc2[t].y;
        scol[t] = n3;

        float r0 = n3, r1 = -n3;
        if (t < 2) {
            const float n3_pph = -2.0f*mp*mp*mh + 2.0f*mp*cph + mh*cpp;
            const float n3_hhp = -2.0f*mh*mh*mp + 2.0f*mh*chp + mp*chh;
            const float n3_hpp = -2.0f*mh*mp*mp + mh*cpp + 2.0f*mp*chp;
            const float vals_pp = -2.0f*n3_pph + chp;
            const float vals_hh =  2.0f*n3_hhp + chp;
            const float vals_hp = -n3_hhp + n3_hpp - chp;
            r0 = (t == 0) ? vals_hh : vals_hp;
            r1 = (t == 0) ? vals_hp : vals_pp;
        }
        srow0[t] = r0;
        srow1[t] = r1;
        if (t == 0) schp[0] = chp;
    }
    __syncthreads();

    // stage 3: write the full 128x128 tile as float4 (32 float4/row, 4096 total)
    float4* __restrict__ onc4 = reinterpret_cast<float4*>(onc);
    const float4 zero4 = make_float4(0.f, 0.f, 0.f, 0.f);
    #pragma unroll
    for (int i = 0; i < 16; ++i) {
        const int f  = i * 256 + t;      // float4 index in tile
        const int r  = f >> 5;           // row
        const int c4 = f & 31;           // float4 column
        float4 v;
        if (r == 0)        v = *reinterpret_cast<const float4*>(&srow0[c4 * 4]);
        else if (r == 1)   v = *reinterpret_cast<const float4*>(&srow1[c4 * 4]);
        else if (c4 == 0)  v = make_float4(scol[r], -scol[r], 0.f, 0.f);
        else               v = zero4;
        onc4[f] = v;
    }

    // muTE row: 32 float4s, only the first is nonzero
    if (t < 32) {
        float4 v = zero4;
        if (t == 0) v = make_float4(schp[0], -schp[0], 0.f, 0.f);
        reinterpret_cast<float4*>(omu)[t] = v;
    }
}

extern "C" void kernel_launch(void* const* d_in, const int* in_sizes, int n_in,
                              void* d_out, int out_size, void* d_ws, size_t ws_size,
                              hipStream_t stream) {
    const float* mu   = (const float*)d_in[0];
    const float* ncov = (const float*)d_in[1];

    const int batch = in_sizes[0] / NTOT;

    float* out_mu   = (float*)d_out;
    float* out_ncov = out_mu + (size_t)batch * NTOT;

    eat_rxn_fused<<<batch, 256, 0, stream>>>(mu, ncov, out_mu, out_ncov);
}

// Round 3
// 69.434 us; speedup vs baseline: 1.1373x; 1.0404x over previous
//
#include <hip/hip_runtime.h>

// EatRxnLayer: h=0 (hunter), p=1 (prey), N=128, BATCH=4096.
// Output = [muTE (B,128) | ncovTE (B,128,128)] fp32, flat.
// ncovTE is zero except rows 0,1 and columns 0,1 (+4 corner cells).
// R1: hipMemsetAsync fill path was the bottleneck -> fused single kernel.
// R2: 72 us ~ 4.7 TB/s mixed; stores all went through L2 (no reuse).
// R3: nontemporal float4 stores (L2 bypass) + nontemporal gather loads.

#define NTOT 128

typedef float f4_t __attribute__((ext_vector_type(4)));
typedef float f2_t __attribute__((ext_vector_type(2)));

__global__ __launch_bounds__(256)
void eat_rxn_fused(const float* __restrict__ mu,
                   const float* __restrict__ ncov,
                   float* __restrict__ out_mu,
                   float* __restrict__ out_ncov) {
    const int b = blockIdx.x;
    const int t = threadIdx.x;

    const float* __restrict__ murow = mu   + (size_t)b * NTOT;
    const float* __restrict__ crow  = ncov + (size_t)b * NTOT * NTOT;
    float* __restrict__ omu = out_mu  + (size_t)b * NTOT;
    float* __restrict__ onc = out_ncov + (size_t)b * NTOT * NTOT;

    __shared__ float  smu[NTOT];
    __shared__ f2_t   sc2[NTOT];     // ncov[b, j, 0:2]
    __shared__ float  srow0[NTOT];   // final ncovTE row 0
    __shared__ float  srow1[NTOT];   // final ncovTE row 1
    __shared__ float  scol[NTOT];    // n3_j (col0 value for rows j>=2; col1 = -n3_j)
    __shared__ float  schp[1];

    // stage 1: load mu row + first-two-columns of ncov (one 8B load per row)
    if (t < NTOT) {
        smu[t] = murow[t];
        sc2[t] = __builtin_nontemporal_load(
                     reinterpret_cast<const f2_t*>(crow + (size_t)t * NTOT));
    }
    __syncthreads();

    const float mh  = smu[0],    mp  = smu[1];
    const float chh = sc2[0].x,  chp = sc2[0].y;
    const float cph = sc2[1].x,  cpp = sc2[1].y;

    // stage 2: per-j third moment n3_j and the 4 corner values
    if (t < NTOT) {
        const float A  = -2.0f * mp * mh + cph;
        const float n3 = smu[t] * A + mp * sc2[t].x + mh * sc2[t].y;
        scol[t] = n3;

        float r0 = n3, r1 = -n3;
        if (t < 2) {
            const float n3_pph = -2.0f*mp*mp*mh + 2.0f*mp*cph + mh*cpp;
            const float n3_hhp = -2.0f*mh*mh*mp + 2.0f*mh*chp + mp*chh;
            const float n3_hpp = -2.0f*mh*mp*mp + mh*cpp + 2.0f*mp*chp;
            const float vals_pp = -2.0f*n3_pph + chp;
            const float vals_hh =  2.0f*n3_hhp + chp;
            const float vals_hp = -n3_hhp + n3_hpp - chp;
            r0 = (t == 0) ? vals_hh : vals_hp;
            r1 = (t == 0) ? vals_hp : vals_pp;
        }
        srow0[t] = r0;
        srow1[t] = r1;
        if (t == 0) schp[0] = chp;
    }
    __syncthreads();

    // stage 3: write the full 128x128 tile as nontemporal float4
    // (32 float4/row, 4096 total, 16 per thread)
    f4_t* __restrict__ onc4 = reinterpret_cast<f4_t*>(onc);
    const f4_t zero4 = {0.f, 0.f, 0.f, 0.f};
    #pragma unroll
    for (int i = 0; i < 16; ++i) {
        const int f  = i * 256 + t;      // float4 index in tile
        const int r  = f >> 5;           // row
        const int c4 = f & 31;           // float4 column
        f4_t v;
        if (r == 0)        v = *reinterpret_cast<const f4_t*>(&srow0[c4 * 4]);
        else if (r == 1)   v = *reinterpret_cast<const f4_t*>(&srow1[c4 * 4]);
        else if (c4 == 0)  v = (f4_t){scol[r], -scol[r], 0.f, 0.f};
        else               v = zero4;
        __builtin_nontemporal_store(v, &onc4[f]);
    }

    // muTE row: 32 float4s, only the first is nonzero
    if (t < 32) {
        f4_t v = zero4;
        if (t == 0) v = (f4_t){schp[0], -schp[0], 0.f, 0.f};
        __builtin_nontemporal_store(v, reinterpret_cast<f4_t*>(omu) + t);
    }
}

extern "C" void kernel_launch(void* const* d_in, const int* in_sizes, int n_in,
                              void* d_out, int out_size, void* d_ws, size_t ws_size,
                              hipStream_t stream) {
    const float* mu   = (const float*)d_in[0];
    const float* ncov = (const float*)d_in[1];

    const int batch = in_sizes[0] / NTOT;

    float* out_mu   = (float*)d_out;
    float* out_ncov = out_mu + (size_t)batch * NTOT;

    eat_rxn_fused<<<batch, 256, 0, stream>>>(mu, ncov, out_mu, out_ncov);
}